// Round 1
// baseline (18996.394 us; speedup 1.0000x reference)
//
#include <hip/hip_runtime.h>
#include <math.h>

// DWM recurrent cell. One workgroup per batch element (64 wgs x 1024 thr),
// all recurrent state in LDS, 256 sequential timesteps per wg.

#define NHEAD 4
#define MSZ   32
#define NADDR 256
#define SEQ   256
#define INDIM 264
#define SU    512
#define DB    256
#define UPDN  424
#define COMBN 904
#define HP    106
#define MEMP  257   // padded row stride for mem (bank-conflict break)
#define WTP   257   // padded row stride for wt-like arrays

__device__ __forceinline__ float sigmoidf_(float x) { return 1.0f / (1.0f + expf(-x)); }
__device__ __forceinline__ float softplusf_(float x) { return fmaxf(x, 0.0f) + log1pf(expf(-fabsf(x))); }

__global__ __launch_bounds__(1024) void dwm_kernel(
    const float* __restrict__ xin,
    const float* __restrict__ Wo, const float* __restrict__ bo,
    const float* __restrict__ Ws, const float* __restrict__ bs,
    const float* __restrict__ Wu, const float* __restrict__ bu,
    float* __restrict__ out)
{
    const int b = blockIdx.x;
    const int tid = threadIdx.x;

    __shared__ float s_mem[MSZ * MEMP];          // 32x256 memory (padded)
    __shared__ float s_wt[NHEAD * WTP];          // head weights w_t
    __shared__ float s_wtdyn[NHEAD * WTP];       // snapshot weights
    __shared__ float s_wtg[NHEAD * WTP];         // gated weights
    __shared__ float s_wts[NHEAD * WTP];         // shifted/sharpened (pre-norm)
    __shared__ float s_logit[NHEAD * WTP];       // content logits
    __shared__ float s_state[SU];
    __shared__ __align__(16) float s_comb[COMBN];
    __shared__ float s_read[NHEAD * MSZ];
    __shared__ float s_upd[UPDN];
    __shared__ float s_erase[NHEAD * MSZ];
    __shared__ float s_khat[NHEAD * MSZ];
    __shared__ float s_cnorm[NADDR];
    __shared__ float s_shift[NHEAD * 3];
    __shared__ float s_jmp[NHEAD * 3];
    __shared__ float s_jd[NHEAD], s_gamma[NHEAD], s_beta[NHEAD], s_g[NHEAD];
    __shared__ float s_smax[NHEAD], s_ssum[NHEAD], s_psum[NHEAD];

    // ---- init carry ----
    if (tid < SU) s_state[tid] = 1.0f;
    {
        int h = tid >> 8, n = tid & 255;
        float v = (n == 0) ? 1.0f : 0.0f;
        s_wt[h * WTP + n] = v;
        s_wtdyn[h * WTP + n] = v;
    }
    for (int idx = tid; idx < MSZ * NADDR; idx += 1024) {
        int m = idx >> 8, n = idx & 255;
        s_mem[m * MEMP + n] = 0.01f;
    }
    __syncthreads();

    for (int t = 0; t < SEQ; ++t) {
        // ---- phase R: read[h][m] = sum_n wt[h][n] * mem[m][n] ----
        {
            int pair = tid >> 3, sub = tid & 7;   // 128 pairs x 8 lanes
            int h = pair >> 5, m = pair & 31;
            float p = 0.0f;
            #pragma unroll 8
            for (int k = 0; k < 32; ++k) {
                int n = sub + (k << 3);
                p = fmaf(s_wt[h * WTP + n], s_mem[m * MEMP + n], p);
            }
            p += __shfl_down(p, 4);
            p += __shfl_down(p, 2);
            p += __shfl_down(p, 1);
            if (sub == 0) s_read[pair] = p;
        }
        __syncthreads();

        // ---- fill comb = [x_t | state | read] ----
        if (tid < INDIM)              s_comb[tid] = xin[((size_t)b * SEQ + t) * INDIM + tid];
        else if (tid < INDIM + SU)    s_comb[tid] = s_state[tid - INDIM];
        else if (tid < COMBN)         s_comb[tid] = s_read[tid - (INDIM + SU)];
        __syncthreads();

        // ---- matvec: 1192 virtual output columns over [Ws|Wo|Wu] ----
        {
            auto matcol = [&](const float* __restrict__ W, const float* __restrict__ bias,
                              int c, const int ncol) -> float {
                float acc = bias[c];
                const float* wp = W + c;
                for (int i = 0; i < COMBN; i += 4) {
                    float4 cb = *(const float4*)&s_comb[i];
                    acc = fmaf(cb.x, wp[0], acc);
                    acc = fmaf(cb.y, wp[ncol], acc);
                    acc = fmaf(cb.z, wp[2 * ncol], acc);
                    acc = fmaf(cb.w, wp[3 * ncol], acc);
                    wp += 4 * ncol;
                }
                return acc;
            };
            for (int v = tid; v < SU + DB + UPDN; v += 1024) {
                if (v < SU) {
                    s_state[v] = sigmoidf_(matcol(Ws, bs, v, SU));
                } else if (v < SU + DB) {
                    int c = v - SU;
                    out[((size_t)b * SEQ + t) * DB + c] = sigmoidf_(matcol(Wo, bo, c, DB));
                } else {
                    int c = v - (SU + DB);
                    s_upd[c] = matcol(Wu, bu, c, UPDN);
                }
            }
        }
        __syncthreads();

        // ---- phase P: per-head parameter transforms ----
        if (tid < NHEAD * MSZ) {
            int h = tid >> 5, e = tid & 31;
            const float* u = &s_upd[h * HP];
            s_erase[h * MSZ + e] = sigmoidf_(u[8 + e]);
            float kv = tanhf(u[72 + e]);
            float ss = kv * kv;
            ss += __shfl_xor(ss, 1);
            ss += __shfl_xor(ss, 2);
            ss += __shfl_xor(ss, 4);
            ss += __shfl_xor(ss, 8);
            ss += __shfl_xor(ss, 16);
            s_khat[h * MSZ + e] = kv / (sqrtf(ss) + 1e-12f);
        }
        if (tid < NHEAD) {
            const float* u = &s_upd[tid * HP];
            float a0 = softplusf_(u[0]), a1 = softplusf_(u[1]), a2 = softplusf_(u[2]);
            float mx = fmaxf(a0, fmaxf(a1, a2));
            float e0 = expf(a0 - mx), e1 = expf(a1 - mx), e2 = expf(a2 - mx);
            float inv = 1.0f / (e0 + e1 + e2);
            s_shift[tid * 3 + 0] = e0 * inv;
            s_shift[tid * 3 + 1] = e1 * inv;
            s_shift[tid * 3 + 2] = e2 * inv;
            s_jd[tid] = sigmoidf_(u[3]);
            float j0 = u[4], j1 = u[5], j2 = u[6];
            float jm = fmaxf(j0, fmaxf(j1, j2));
            float f0 = expf(j0 - jm), f1 = expf(j1 - jm), f2 = expf(j2 - jm);
            float jinv = 1.0f / (f0 + f1 + f2);
            s_jmp[tid * 3 + 0] = f0 * jinv;
            s_jmp[tid * 3 + 1] = f1 * jinv;
            s_jmp[tid * 3 + 2] = f2 * jinv;
            s_gamma[tid] = 1.0f + softplusf_(u[7]);
            s_beta[tid] = softplusf_(u[104]);
            s_g[tid] = sigmoidf_(u[105]);
        }
        __syncthreads();

        // ---- phase W: memory erase/add (uses OLD wt) ----
        #pragma unroll
        for (int r = 0; r < 8; ++r) {
            int idx = tid + (r << 10);
            int m = idx >> 8, n = idx & 255;
            float w0 = s_wt[0 * WTP + n], w1 = s_wt[1 * WTP + n];
            float w2 = s_wt[2 * WTP + n], w3 = s_wt[3 * WTP + n];
            float prod = (1.0f - s_erase[0 * MSZ + m] * w0) * (1.0f - s_erase[1 * MSZ + m] * w1)
                       * (1.0f - s_erase[2 * MSZ + m] * w2) * (1.0f - s_erase[3 * MSZ + m] * w3);
            float addv = s_upd[0 * HP + 40 + m] * w0 + s_upd[1 * HP + 40 + m] * w1
                       + s_upd[2 * HP + 40 + m] * w2 + s_upd[3 * HP + 40 + m] * w3;
            s_mem[m * MEMP + n] = s_mem[m * MEMP + n] * prod + addv;
        }
        __syncthreads();

        // ---- column norms of updated mem ----
        if (tid < NADDR) {
            float ss = 0.0f;
            #pragma unroll 8
            for (int m = 0; m < MSZ; ++m) {
                float v = s_mem[m * MEMP + tid];
                ss = fmaf(v, v, ss);
            }
            s_cnorm[tid] = sqrtf(ss) + 1e-12f;
        }
        __syncthreads();

        // ---- content logits ----
        {
            int h = tid >> 8, n = tid & 255;
            float d = 0.0f;
            #pragma unroll 8
            for (int m = 0; m < MSZ; ++m)
                d = fmaf(s_khat[h * MSZ + m], s_mem[m * MEMP + n], d);
            s_logit[h * WTP + n] = s_beta[h] * d / s_cnorm[n];
        }
        __syncthreads();

        // ---- per-head softmax reduce (wave h handles head h) ----
        if (tid < 256) {
            int h = tid >> 6, lane = tid & 63;
            float mx = -1e30f;
            #pragma unroll
            for (int k = 0; k < 4; ++k) mx = fmaxf(mx, s_logit[h * WTP + lane + (k << 6)]);
            for (int m2 = 32; m2 >= 1; m2 >>= 1) mx = fmaxf(mx, __shfl_xor(mx, m2));
            float sm = 0.0f;
            #pragma unroll
            for (int k = 0; k < 4; ++k) sm += expf(s_logit[h * WTP + lane + (k << 6)] - mx);
            for (int m2 = 32; m2 >= 1; m2 >>= 1) sm += __shfl_xor(sm, m2);
            if (lane == 0) { s_smax[h] = mx; s_ssum[h] = sm; }
        }
        __syncthreads();

        // ---- gate: wt_g = g*softmax + (1-g)*wt ----
        {
            int h = tid >> 8, n = tid & 255;
            float wc = expf(s_logit[h * WTP + n] - s_smax[h]) / s_ssum[h];
            s_wtg[h * WTP + n] = s_g[h] * wc + (1.0f - s_g[h]) * s_wt[h * WTP + n];
        }
        __syncthreads();

        // ---- circular conv (S=3) + sharpen ----
        {
            int h = tid >> 8, n = tid & 255;
            float v = s_shift[h * 3 + 0] * s_wtg[h * WTP + ((n + 255) & 255)]
                    + s_shift[h * 3 + 1] * s_wtg[h * WTP + n]
                    + s_shift[h * 3 + 2] * s_wtg[h * WTP + ((n + 1) & 255)];
            s_wts[h * WTP + n] = powf(v + 1e-12f, s_gamma[h]);
        }
        __syncthreads();
        if (tid < 256) {
            int h = tid >> 6, lane = tid & 63;
            float sm = 0.0f;
            #pragma unroll
            for (int k = 0; k < 4; ++k) sm += s_wts[h * WTP + lane + (k << 6)];
            for (int m2 = 32; m2 >= 1; m2 >>= 1) sm += __shfl_xor(sm, m2);
            if (lane == 0) s_psum[h] = sm;
        }
        __syncthreads();

        // ---- snapshot + jump; write new wt, wt_dyn ----
        {
            int h = tid >> 8, n = tid & 255;
            float ws = s_wts[h * WTP + n] / s_psum[h];
            float jd = s_jd[h];
            float dyn = (1.0f - jd) * s_wtdyn[h * WTP + n] + jd * ws;
            s_wtdyn[h * WTP + n] = dyn;
            float w0v = (n == 0) ? 1.0f : 0.0f;
            s_wt[h * WTP + n] = s_jmp[h * 3 + 0] * ws + s_jmp[h * 3 + 1] * dyn + s_jmp[h * 3 + 2] * w0v;
        }
        __syncthreads();
    }
}

extern "C" void kernel_launch(void* const* d_in, const int* in_sizes, int n_in,
                              void* d_out, int out_size, void* d_ws, size_t ws_size,
                              hipStream_t stream) {
    const float* x  = (const float*)d_in[0];
    const float* Wo = (const float*)d_in[1];
    const float* bo = (const float*)d_in[2];
    const float* Ws = (const float*)d_in[3];
    const float* bs = (const float*)d_in[4];
    const float* Wu = (const float*)d_in[5];
    const float* bu = (const float*)d_in[6];
    float* out = (float*)d_out;
    hipLaunchKernelGGL(dwm_kernel, dim3(64), dim3(1024), 0, stream,
                       x, Wo, bo, Ws, bs, Wu, bu, out);
}